// Round 9
// baseline (59.472 us; speedup 1.0000x reference)
//
#include <hip/hip_runtime.h>

// PointNet++ grouping: ball query (radius 0.2, nsample 64) + gather + concat.
// Shapes fixed by setup_inputs(): B=4, N=16384, npoint=2048, C=64.
// out[b][j][c][s]: c in [0,3) = xyz[idx]-new_xyz, c in [3,67) = features[c-3][idx].
//
// Structure (round 9 = round 7 + block-shared query scan):
//   Kernel 1: transpose features (B,C,N) -> ft (B,N,C) in ws, XCD-pinned.
//   Kernel 2: fused query + cooperative gather (round-7 gather unchanged).
//     QUERY IS NOW BLOCK-SHARED: the 4 waves scan the same chunk sequence,
//     so each 256-pt chunk (3KB) is loaded from global ONCE per block into
//     LDS (192 threads x float4), then all 4 waves test their centers from
//     LDS (AoS stride-3 reads = 2-way bank alias = free). Next chunk's
//     global loads issue before the ready-barrier (latency hides under
//     testing). Cuts query L2 traffic ~540 MB -> ~200 MB and query VMEM
//     instruction count ~4x; block exits when all 4 waves found 64 (LDS
//     flags). Chunk buffer overlays the gather's stile (barrier-separated).

#define BB 4
#define NN 16384
#define NP 2048
#define CC 64
#define NS 64
#define CH (3 + CC)
#define NCHUNK (NN / 256)   // 64 chunks of 256 points
#define ST 65               // stile row stride (floats); conflict-free

typedef float f32x4 __attribute__((ext_vector_type(4)));

// ---------- Kernel 1: features (B,C,N) -> ft (B,N,C), XCD-pinned ----------
__global__ __launch_bounds__(256) void pn2_transpose_kernel(
    const float* __restrict__ f, float* __restrict__ ft)
{
    __shared__ float tile[CC][65];           // +1 pad: conflict-free both ways
    const int g = blockIdx.x;                // 1024 blocks
    const int xcd = g & 7;
    const int b = xcd >> 1;                  // batch pinned to XCD pair
    const int tidx = ((xcd & 1) << 7) + (g >> 3);   // 0..255
    const int n0 = tidx << 6;
    const int col = threadIdx.x & 63;
    const int r4  = threadIdx.x >> 6;        // 0..3
    const float* src = f + (size_t)b * CC * NN;
#pragma unroll
    for (int i = 0; i < 16; ++i) {
        const int c = r4 + i * 4;
        tile[c][col] = __builtin_nontemporal_load(&src[(size_t)c * NN + n0 + col]);
    }
    __syncthreads();
    float* dst = ft + ((size_t)b * NN + n0) * CC;
#pragma unroll
    for (int i = 0; i < 16; ++i) {
        const int n = r4 + i * 4;
        dst[(size_t)n * CC + col] = tile[col][n];        // coalesced along c
    }
}

// ---------- Kernel 2: fused block-shared query + cooperative gather ----------
__global__ __launch_bounds__(256, 4) void pn2_qg_kernel(
    const float* __restrict__ xyz,       // (B, N, 3)
    const float* __restrict__ new_xyz,   // (B, NP, 3)
    const float* __restrict__ ft,        // ws: (B, N, C)
    float* __restrict__ out)             // (B, NP, CH, NS)
{
    __shared__ int sidx[4][NS];
    __shared__ int sdone[4];
    // stile (gather transpose tile) overlays the query chunk buffer; the two
    // uses are separated by the block-collective exit barrier.
    __shared__ __align__(16) float stile[4][32 * ST];    // 33.3 KB

    const int tid = threadIdx.x;
    const int lane = tid & 63;
    const int wave = tid >> 6;

    // XCD batch pinning (matches transpose): bijective over 2048 blocks.
    const int g = blockIdx.x;
    const int xcd = g & 7;
    const int cg = ((xcd >> 1) << 9) + ((xcd & 1) << 8) + (g >> 3);
    const int center = cg * 4 + wave;           // 0 .. B*NP-1
    const int b = center >> 11;
    const int j = center & (NP - 1);

    const float r2 = 0.04f;                     // f32(0.2*0.2)
    const float* q = new_xyz + ((size_t)b * NP + j) * 3;
    const float cx = q[0], cy = q[1], cz = q[2];

    const float* xb = xyz + (size_t)b * NN * 3;
    const float4* x4 = (const float4*)xb;       // chunk c = float4 [192c,192c+192)
    int* widx = sidx[wave];
    float* xyzbuf = &stile[0][0];               // 768 floats (3 KB) overlay
    float4* xb4 = (float4*)xyzbuf;

    if (tid < 4) sdone[tid] = 0;

    // ---- block-shared query scan ----
    const unsigned long long low = (1ull << lane) - 1ull;
    int found = 0;
    bool mydone = false;
    int it = 0;
    float4 reg;
    if (tid < 192) reg = x4[tid];               // preload chunk 0

    while (true) {
        __syncthreads();   // (a) prev chunk's tests done; sdone visible
        if (it == NCHUNK ||
            (sdone[0] + sdone[1] + sdone[2] + sdone[3]) == 4) break;
        if (tid < 192) {
            xb4[tid] = reg;                     // publish chunk it
            const int nit = (it + 1 < NCHUNK) ? (it + 1) : it;
            reg = x4[(size_t)nit * 192 + tid];  // issue next chunk's loads
        }
        __syncthreads();   // (b) chunk ready in LDS
        if (!mydone) {
#pragma unroll
            for (int k = 0; k < 4; ++k) {       // groups in index order
                const int p = k * 64 + lane;    // AoS stride-3: 2-way = free
                const float dx = xyzbuf[3 * p + 0] - cx;
                const float dy = xyzbuf[3 * p + 1] - cy;
                const float dz = xyzbuf[3 * p + 2] - cz;
                // match numpy: plain f32 mul/add, left-to-right, NO fma
                const float d2 = __fadd_rn(__fadd_rn(__fmul_rn(dx, dx),
                                                     __fmul_rn(dy, dy)),
                                           __fmul_rn(dz, dz));
                const bool within = d2 < r2;
                const unsigned long long m = __ballot(within);
                const int pos = found + (int)__popcll(m & low);
                if (within && pos < NS) widx[pos] = it * 256 + p;
                found += (int)__popcll(m);      // wave-uniform
            }
            if (found >= NS) mydone = true;
            if (lane == 0) sdone[wave] = mydone ? 1 : 0;
        }
        ++it;
    }

    // ref fill semantics: pad with first found idx, 0 if none found
    int myidx = 0;
    if (found > 0) {
        const int first = widx[0];
        myidx = (lane < found) ? widx[lane] : first;
    }
    widx[lane] = myidx;   // full 64-slot idx table for the cooperative gather

    // ---- xyz channels (lane = sample slot; 256B-coalesced NT stores)
    const float* pp = xb + (size_t)myidx * 3;
    float* ob = out + (size_t)center * CH * NS;
    __builtin_nontemporal_store(pp[0] - cx, ob + 0 * NS + lane);
    __builtin_nontemporal_store(pp[1] - cy, ob + 1 * NS + lane);
    __builtin_nontemporal_store(pp[2] - cz, ob + 2 * NS + lane);

    // ---- cooperative feature gather (unchanged from round 7)
    const float* ftb = ft + (size_t)b * NN * CC;
    float* tw = stile[wave];
    const int sub  = lane & 15;   // 16B chunk within a row
    const int rsub = lane >> 4;   // which of 4 rows this instr covers
    const int sq   = lane & 7;    // sample quad within half
    const int cc8  = lane >> 3;   // channel offset within group of 8

#pragma unroll
    for (int h = 0; h < 2; ++h) {
        int ridx[8];
#pragma unroll
        for (int i = 0; i < 8; ++i) ridx[i] = widx[32 * h + 4 * i + rsub];
        float4 v[8];
#pragma unroll
        for (int i = 0; i < 8; ++i)   // 8 dwordx4, contiguous 256B lane groups
            v[i] = *(const float4*)(ftb + (size_t)ridx[i] * CC + 4 * sub);
#pragma unroll
        for (int i = 0; i < 8; ++i) { // tile[sample][channel], <=2-way banks
            float* tr = tw + (4 * i + rsub) * ST + 4 * sub;
            tr[0] = v[i].x; tr[1] = v[i].y; tr[2] = v[i].z; tr[3] = v[i].w;
        }
#pragma unroll
        for (int t = 0; t < 8; ++t) { // 8 dwordx4 NT stores per half
            const int c = 8 * t + cc8;
            f32x4 u;
            u.x = tw[(4 * sq + 0) * ST + c];
            u.y = tw[(4 * sq + 1) * ST + c];
            u.z = tw[(4 * sq + 2) * ST + c];
            u.w = tw[(4 * sq + 3) * ST + c];
            float* o = ob + (size_t)(3 + c) * NS + 32 * h + 4 * sq;  // 16B aligned
            __builtin_nontemporal_store(u, (f32x4*)o);
        }
    }
}

// ---------- Fallback (ws too small): round-1 direct-gather kernel ----------
__global__ __launch_bounds__(256, 4) void pn2_group_kernel(
    const float* __restrict__ xyz, const float* __restrict__ new_xyz,
    const float* __restrict__ features, float* __restrict__ out)
{
    __shared__ int sidx[4][NS];
    const int lane = threadIdx.x & 63;
    const int wave = threadIdx.x >> 6;
    const int center = blockIdx.x * 4 + wave;
    const int b = center >> 11;
    const int j = center & (NP - 1);
    const float r2 = 0.04f;
    const float* q = new_xyz + ((size_t)b * NP + j) * 3;
    const float cx = q[0], cy = q[1], cz = q[2];
    int* widx = sidx[wave];
    int found = 0;
    for (int it = 0; it < NN / 64; ++it) {
        const int n = it * 64 + lane;
        const float* p = xyz + ((size_t)b * NN + n) * 3;
        const float dx = p[0] - cx, dy = p[1] - cy, dz = p[2] - cz;
        const float d2 = __fadd_rn(__fadd_rn(__fmul_rn(dx, dx), __fmul_rn(dy, dy)),
                                   __fmul_rn(dz, dz));
        const bool within = d2 < r2;
        const unsigned long long mask = __ballot(within);
        const int pos = found + (int)__popcll(mask & ((1ull << lane) - 1ull));
        if (within && pos < NS) widx[pos] = n;
        found += (int)__popcll(mask);
        if (found >= NS) break;
    }
    int myidx = 0;
    if (found > 0) {
        const int first = widx[0];
        myidx = (lane < found) ? widx[lane] : first;
    }
    const float* pp = xyz + ((size_t)b * NN + myidx) * 3;
    float* ob = out + (((size_t)b * NP + j) * (size_t)CH) * NS + lane;
    ob[0 * NS] = pp[0] - cx;
    ob[1 * NS] = pp[1] - cy;
    ob[2 * NS] = pp[2] - cz;
    const float* fb = features + (size_t)b * CC * NN + myidx;
#pragma unroll 8
    for (int c = 0; c < CC; ++c) ob[(size_t)(3 + c) * NS] = fb[(size_t)c * NN];
}

extern "C" void kernel_launch(void* const* d_in, const int* in_sizes, int n_in,
                              void* d_out, int out_size, void* d_ws, size_t ws_size,
                              hipStream_t stream) {
    const float* xyz      = (const float*)d_in[0];
    const float* new_xyz  = (const float*)d_in[1];
    const float* features = (const float*)d_in[2];
    float* out = (float*)d_out;

    const size_t ft_bytes = (size_t)BB * NN * CC * sizeof(float);   // 16.8 MB

    if (ws_size >= ft_bytes) {
        float* ft = (float*)d_ws;
        pn2_transpose_kernel<<<BB * 256, 256, 0, stream>>>(features, ft);
        pn2_qg_kernel<<<BB * NP / 4, 256, 0, stream>>>(xyz, new_xyz, ft, out);
    } else {
        pn2_group_kernel<<<BB * NP / 4, 256, 0, stream>>>(xyz, new_xyz, features, out);
    }
}